// Round 1
// baseline (197.703 us; speedup 1.0000x reference)
//
#include <hip/hip_runtime.h>

// Problem constants (match reference file)
constexpr int Dv = 160, Hv = 192, Wv = 160;
constexpr int NN = Dv * Hv * Wv;  // 4,915,200 voxels

// Trilinear sample, 1 channel, padding='zeros', align_corners=False.
// x,y,z are grid_sample coords (x ~ W axis, y ~ H axis, z ~ D axis).
__device__ __forceinline__ float tri_sample_1c(const float* __restrict__ v,
                                               float x, float y, float z) {
  float ix = ((x + 1.0f) * (float)Wv - 1.0f) * 0.5f;
  float iy = ((y + 1.0f) * (float)Hv - 1.0f) * 0.5f;
  float iz = ((z + 1.0f) * (float)Dv - 1.0f) * 0.5f;
  float fx = floorf(ix), fy = floorf(iy), fz = floorf(iz);
  float wx = ix - fx, wy = iy - fy, wz = iz - fz;
  int x0 = (int)fx, y0 = (int)fy, z0 = (int)fz;
  float acc = 0.0f;
#pragma unroll
  for (int c = 0; c < 8; ++c) {
    const int dz = (c >> 2) & 1, dy = (c >> 1) & 1, dx = c & 1;
    int zi = z0 + dz, yi = y0 + dy, xi = x0 + dx;
    if ((unsigned)zi < (unsigned)Dv && (unsigned)yi < (unsigned)Hv &&
        (unsigned)xi < (unsigned)Wv) {
      float wgt = (dz ? wz : 1.0f - wz) * (dy ? wy : 1.0f - wy) *
                  (dx ? wx : 1.0f - wx);
      acc += wgt * v[(zi * Hv + yi) * Wv + xi];
    }
  }
  return acc;
}

// Trilinear sample of a 3-channel volume (channels stride NN apart).
// Early-out when the entire 2x2x2 support is out of bounds — true for
// essentially every voxel because grid2 is (quirkily) unnormalized.
__device__ __forceinline__ void tri_sample_3c(const float* __restrict__ v,
                                              float x, float y, float z,
                                              float& o0, float& o1, float& o2) {
  o0 = 0.0f; o1 = 0.0f; o2 = 0.0f;
  float ix = ((x + 1.0f) * (float)Wv - 1.0f) * 0.5f;
  float iy = ((y + 1.0f) * (float)Hv - 1.0f) * 0.5f;
  float iz = ((z + 1.0f) * (float)Dv - 1.0f) * 0.5f;
  float fx = floorf(ix), fy = floorf(iy), fz = floorf(iz);
  float wx = ix - fx, wy = iy - fy, wz = iz - fz;
  int x0 = (int)fx, y0 = (int)fy, z0 = (int)fz;
  // any corner possibly in-bounds?
  if (x0 < -1 || x0 >= Wv || y0 < -1 || y0 >= Hv || z0 < -1 || z0 >= Dv)
    return;
#pragma unroll
  for (int c = 0; c < 8; ++c) {
    const int dz = (c >> 2) & 1, dy = (c >> 1) & 1, dx = c & 1;
    int zi = z0 + dz, yi = y0 + dy, xi = x0 + dx;
    if ((unsigned)zi < (unsigned)Dv && (unsigned)yi < (unsigned)Hv &&
        (unsigned)xi < (unsigned)Wv) {
      float wgt = (dz ? wz : 1.0f - wz) * (dy ? wy : 1.0f - wy) *
                  (dx ? wx : 1.0f - wx);
      int lin = (zi * Hv + yi) * Wv + xi;
      o0 += wgt * v[lin];
      o1 += wgt * v[NN + lin];
      o2 += wgt * v[2 * NN + lin];
    }
  }
}

__global__ __launch_bounds__(256)
void st_fused_kernel(const float* __restrict__ src,
                     const float* __restrict__ flow1,
                     const float* __restrict__ flow2,
                     const float* __restrict__ rfp,
                     float* __restrict__ out) {
  int idx = blockIdx.x * blockDim.x + threadIdx.x;
  if (idx >= NN) return;
  const float rf = rfp[0];

  int w = idx % Wv;
  int t = idx / Wv;
  int h = t % Hv;
  int d = t / Hv;

  // flow2 channels are (d, h, w)
  float f2_0 = flow2[idx];
  float f2_1 = flow2[NN + idx];
  float f2_2 = flow2[2 * NN + idx];

  // grid2 (x,y,z) = (w + rf*f2_w, h + rf*f2_h, d + rf*f2_d)  [NOT normalized]
  float gx = (float)w + rf * f2_2;
  float gy = (float)h + rf * f2_1;
  float gz = (float)d + rf * f2_0;

  float w0, w1, w2;  // flow1 warped, channels (d,h,w) order of flow1 storage
  tri_sample_3c(flow1, gx, gy, gz, w0, w1, w2);

  float of0 = w0 + f2_0;
  float of1 = w1 + f2_1;
  float of2 = w2 + f2_2;

  // out_flow -> out[NN .. 4NN)
  out[NN + idx] = of0;
  out[2 * NN + idx] = of1;
  out[3 * NN + idx] = of2;

  // new_locs_total, channels (d,h,w), denom (D-1, H-1, W-1)
  float nl0 = 2.0f * (((float)d + of0 * rf) / (float)(Dv - 1) - 0.5f);
  float nl1 = 2.0f * (((float)h + of1 * rf) / (float)(Hv - 1) - 0.5f);
  float nl2 = 2.0f * (((float)w + of2 * rf) / (float)(Wv - 1) - 0.5f);

  // to_xyz: (x,y,z) = (channel 2, channel 1, channel 0)
  float img = tri_sample_1c(src, nl2, nl1, nl0);
  out[idx] = img;
}

extern "C" void kernel_launch(void* const* d_in, const int* in_sizes, int n_in,
                              void* d_out, int out_size, void* d_ws, size_t ws_size,
                              hipStream_t stream) {
  const float* src   = (const float*)d_in[0];
  const float* flow1 = (const float*)d_in[1];
  const float* flow2 = (const float*)d_in[2];
  const float* rfp   = (const float*)d_in[3];
  float* out = (float*)d_out;

  const int threads = 256;
  const int blocks = (NN + threads - 1) / threads;
  hipLaunchKernelGGL(st_fused_kernel, dim3(blocks), dim3(threads), 0, stream,
                     src, flow1, flow2, rfp, out);
}